// Round 7
// baseline (824.429 us; speedup 1.0000x reference)
//
#include <hip/hip_runtime.h>
#include <hip/hip_bf16.h>

// Fused GRU-like cell: 200000 rows, IN=HID=256, fp32 in/out, bf16 MFMA compute.
// Kernel 1 (wconv): fp32->bf16 weights, fragment-packed; combined biases.
// Kernel 2 (gru): BM=32 rows/block, 256 threads (4 waves), LDS 32 KB.
//   launch_bounds(256,3): 170 regs/wave (no spill - r1-verified regime) AND
//   3 blocks/CU for cross-block latency hiding. Passes:
//   P1 : z,r merged (K=512); tail: zpk=bf16(z), part=bf16((1-z)*h), rh=r*h->LDS
//   P23: cand = [x|rh]·Bh^T (K=512) -> bf16 into dead x-region
//   P4 : gv = sigmoid(cand·G^T + bg)  (K=256)
//   P5 : lv = cand·L^T + bl; out = z*(lv*gv) + part

typedef short bf16x8 __attribute__((ext_vector_type(8)));   // 8 bf16 = 4 VGPRs
typedef float f32x4  __attribute__((ext_vector_type(4)));

__device__ __forceinline__ unsigned int rne_bf16(float f) {
  unsigned int u = __builtin_bit_cast(unsigned int, f);
  return (u + 0x7fffu + ((u >> 16) & 1u)) >> 16;
}
__device__ __forceinline__ unsigned int pack2(float a, float b) {
  return rne_bf16(a) | (rne_bf16(b) << 16);
}
__device__ __forceinline__ float bf2f(unsigned short s) {
  unsigned int u = ((unsigned int)s) << 16;
  return __builtin_bit_cast(float, u);
}
__device__ __forceinline__ float sigmoidf_(float v) {
  return 1.f / (1.f + __expf(-v));
}

// Fragment packing: frag f holds 8 bf16 for lane=f&63 of tile (nt,kt):
// f = base + (nt*KT + kt)*64 + lane, n = nt*16+(lane&15), k = kt*32+(lane>>4)*8.
// Frag bases (in frags): Bz 0, Br 16384, Bh 32768, G 49152, L 57344.
// fp32 biases at byte 1048576.
__global__ void wconv_kernel(const float* Wz, const float* Uz, const float* Wr, const float* Ur,
                             const float* Wh, const float* Uh, const float* G, const float* L,
                             const float* bWz, const float* bUz, const float* bWr, const float* bUr,
                             const float* bWh, const float* bUh, const float* bG, const float* bL,
                             const float* bias_h,
                             unsigned short* wb, float* bout) {
  int f = blockIdx.x * blockDim.x + threadIdx.x;   // 65536 fragments
  const float* A; const float* B = nullptr;
  int rel; bool k512;
  if (f < 16384)      { A = Wz; B = Uz; rel = f;         k512 = true;  }
  else if (f < 32768) { A = Wr; B = Ur; rel = f - 16384; k512 = true;  }
  else if (f < 49152) { A = Wh; B = Uh; rel = f - 32768; k512 = true;  }
  else if (f < 57344) { A = G;          rel = f - 49152; k512 = false; }
  else                { A = L;          rel = f - 57344; k512 = false; }
  int lane = rel & 63, tile = rel >> 6;
  int kt = k512 ? (tile & 15) : (tile & 7);
  int nt = k512 ? (tile >> 4) : (tile >> 3);
  int n = nt * 16 + (lane & 15);
  int k0 = kt * 32 + (lane >> 4) * 8;
  unsigned short tmp[8];
#pragma unroll
  for (int j = 0; j < 8; ++j) {
    int k = k0 + j;
    float v = (k < 256) ? A[n * 256 + k] : B[n * 256 + (k - 256)];
    tmp[j] = (unsigned short)rne_bf16(v);
  }
  *reinterpret_cast<uint4*>(wb + (size_t)f * 8) = *reinterpret_cast<const uint4*>(tmp);

  if (f < 256) {
    bout[f]        = bWz[f] + bUz[f];
    bout[256 + f]  = bWr[f] + bUr[f];
    bout[512 + f]  = bWh[f] + bUh[f] + bias_h[f];
    bout[768 + f]  = bG[f];
    bout[1024 + f] = bL[f];
  }
}

// Main fused kernel. 256 threads (4 waves). BM=32 rows/block.
// Wave w owns output cols [64w, 64w+64) (ct=0..3). MFMA 16x16x32 bf16.
// LDS xh[32][512] bf16, XOR-swizzled 16B chunks: chunks 0..31 = x (later cand),
// chunks 32..63 = h (later rh).
__global__ __launch_bounds__(256, 3) void gru_kernel(
    const float* __restrict__ x, const float* __restrict__ h,
    const unsigned short* __restrict__ wb,
    const float* __restrict__ bia,
    float* __restrict__ out)
{
  __shared__ unsigned short xh[32 * 512];    // 32 KB

  const int tid  = threadIdx.x;
  const int lane = tid & 63;
  const int wave = tid >> 6;
  const int q    = lane >> 4;     // quarter-wave id
  const int lr   = lane & 15;
  const long row0 = (long)blockIdx.x * 32;

  // ---------------- P0: stage x,h -> LDS bf16 (swizzled) ----------------
#pragma unroll
  for (int i = 0; i < 4; ++i) {
    int c = tid + i * 256;               // 32 rows x 32 chunks
    int r = c >> 5, c8 = c & 31;
    const float4* p = reinterpret_cast<const float4*>(x + (row0 + r) * 256 + c8 * 8);
    float4 v0 = p[0], v1 = p[1];
    uint4 w;
    w.x = pack2(v0.x, v0.y); w.y = pack2(v0.z, v0.w);
    w.z = pack2(v1.x, v1.y); w.w = pack2(v1.z, v1.w);
    reinterpret_cast<uint4*>(xh)[r * 64 + (c8 ^ (r & 7))] = w;
  }
#pragma unroll
  for (int i = 0; i < 4; ++i) {
    int c = tid + i * 256;
    int r = c >> 5, c8 = c & 31;
    const float4* p = reinterpret_cast<const float4*>(h + (row0 + r) * 256 + c8 * 8);
    float4 v0 = p[0], v1 = p[1];
    uint4 w;
    w.x = pack2(v0.x, v0.y); w.y = pack2(v0.z, v0.w);
    w.z = pack2(v1.x, v1.y); w.w = pack2(v1.z, v1.w);
    reinterpret_cast<uint4*>(xh)[r * 64 + ((32 + c8) ^ (r & 7))] = w;
  }
  __syncthreads();

  const unsigned short* Bz = wb;                    // frag-packed bases (shorts)
  const unsigned short* Br = wb + 131072;
  const unsigned short* Bh = wb + 262144;
  const unsigned short* Gw = wb + 393216;
  const unsigned short* Lw = wb + 458752;

  auto ldsA = [&](int mt, int ks) -> bf16x8 {  // A frag, chunk ks*4+q
    int r = mt * 16 + lr;
    int kc = ks * 4 + q;
    return reinterpret_cast<const bf16x8*>(xh)[r * 64 + (kc ^ (r & 7))];
  };
  auto ldB = [&](const unsigned short* base, int KT, int ct, int ks) -> bf16x8 {
    int nt = wave * 4 + ct;
    return reinterpret_cast<const bf16x8*>(base)[(nt * KT + ks) * 64 + lane];
  };

  const int col0 = wave * 64 + lr;      // ct=0 column

  // ---------------- P1: merged z + r (K=512) ----------------
  unsigned int zpk[16], part[16];
  {
    f32x4 az[2][4] = {}; f32x4 ar[2][4] = {};
#pragma unroll
    for (int ks = 0; ks < 16; ++ks) {
      bf16x8 a0 = ldsA(0, ks), a1 = ldsA(1, ks);
#pragma unroll
      for (int ct = 0; ct < 4; ++ct) {
        bf16x8 bz = ldB(Bz, 16, ct, ks);
        az[0][ct] = __builtin_amdgcn_mfma_f32_16x16x32_bf16(a0, bz, az[0][ct], 0, 0, 0);
        az[1][ct] = __builtin_amdgcn_mfma_f32_16x16x32_bf16(a1, bz, az[1][ct], 0, 0, 0);
        bf16x8 br = ldB(Br, 16, ct, ks);
        ar[0][ct] = __builtin_amdgcn_mfma_f32_16x16x32_bf16(a0, br, ar[0][ct], 0, 0, 0);
        ar[1][ct] = __builtin_amdgcn_mfma_f32_16x16x32_bf16(a1, br, ar[1][ct], 0, 0, 0);
      }
    }
    // tail: zpk = bf16(z); part = bf16((1-z)*h); rhpk = bf16(r*h)
    unsigned int rhpk[16];
#pragma unroll
    for (int mt = 0; mt < 2; ++mt) {
#pragma unroll
      for (int ct = 0; ct < 4; ++ct) {
        int cg = col0 + ct * 16;
        float bzc = bia[cg];
        float brc = bia[256 + cg];
        int hc = 32 + (cg >> 3);
#pragma unroll
        for (int ii = 0; ii < 2; ++ii) {
          int rl0 = mt * 16 + q * 4 + 2 * ii;
          float h0 = bf2f(xh[rl0 * 512       + (hc ^ (rl0 & 7))       * 8 + (cg & 7)]);
          float h1 = bf2f(xh[(rl0 + 1) * 512 + (hc ^ ((rl0 + 1) & 7)) * 8 + (cg & 7)]);
          float z0 = sigmoidf_(az[mt][ct][2 * ii]     + bzc);
          float z1 = sigmoidf_(az[mt][ct][2 * ii + 1] + bzc);
          zpk[(mt * 4 + ct) * 2 + ii]  = pack2(z0, z1);
          part[(mt * 4 + ct) * 2 + ii] = pack2((1.f - z0) * h0, (1.f - z1) * h1);
          float r0 = sigmoidf_(ar[mt][ct][2 * ii]     + brc);
          float r1 = sigmoidf_(ar[mt][ct][2 * ii + 1] + brc);
          rhpk[(mt * 4 + ct) * 2 + ii] = pack2(r0 * h0, r1 * h1);
        }
      }
    }
    __syncthreads();   // all waves done reading h-region A-frags
    // write rh into the dead h-region (chunks 32..63)
#pragma unroll
    for (int mt = 0; mt < 2; ++mt) {
#pragma unroll
      for (int ct = 0; ct < 4; ++ct) {
        int cg = col0 + ct * 16;
        int hc = 32 + (cg >> 3);
#pragma unroll
        for (int ii = 0; ii < 2; ++ii) {
          unsigned int v = rhpk[(mt * 4 + ct) * 2 + ii];
          int rl0 = mt * 16 + q * 4 + 2 * ii;
          xh[rl0 * 512       + (hc ^ (rl0 & 7))       * 8 + (cg & 7)] = (unsigned short)(v & 0xffffu);
          xh[(rl0 + 1) * 512 + (hc ^ ((rl0 + 1) & 7)) * 8 + (cg & 7)] = (unsigned short)(v >> 16);
        }
      }
    }
  }
  __syncthreads();

  // ---------------- P23: cand = [x|rh] @ Bh^T (K=512) ----------------
  {
    f32x4 ac[2][4] = {};
#pragma unroll
    for (int ks = 0; ks < 16; ++ks) {
      bf16x8 a0 = ldsA(0, ks), a1 = ldsA(1, ks);
#pragma unroll
      for (int ct = 0; ct < 4; ++ct) {
        bf16x8 b = ldB(Bh, 16, ct, ks);
        ac[0][ct] = __builtin_amdgcn_mfma_f32_16x16x32_bf16(a0, b, ac[0][ct], 0, 0, 0);
        ac[1][ct] = __builtin_amdgcn_mfma_f32_16x16x32_bf16(a1, b, ac[1][ct], 0, 0, 0);
      }
    }
    __syncthreads();   // all waves done reading x-region A-frags
    // cand -> bf16 into the dead x-region (chunks 0..31)
#pragma unroll
    for (int mt = 0; mt < 2; ++mt) {
#pragma unroll
      for (int ct = 0; ct < 4; ++ct) {
        int cg = col0 + ct * 16;
        float bcc = bia[512 + cg];
#pragma unroll
        for (int i = 0; i < 4; ++i) {
          int rl = mt * 16 + q * 4 + i;
          float cd = ac[mt][ct][i] + bcc;
          xh[rl * 512 + (((cg >> 3) ^ (rl & 7)) * 8) + (cg & 7)] = (unsigned short)rne_bf16(cd);
        }
      }
    }
  }
  __syncthreads();

  // ---------------- P4: gv = sigmoid(cand @ G^T + bg) (K=256) ----------------
  f32x4 gv[2][4];
  {
    f32x4 acc[2][4] = {};
#pragma unroll
    for (int ks = 0; ks < 8; ++ks) {
      bf16x8 a0 = ldsA(0, ks), a1 = ldsA(1, ks);
#pragma unroll
      for (int ct = 0; ct < 4; ++ct) {
        bf16x8 b = ldB(Gw, 8, ct, ks);
        acc[0][ct] = __builtin_amdgcn_mfma_f32_16x16x32_bf16(a0, b, acc[0][ct], 0, 0, 0);
        acc[1][ct] = __builtin_amdgcn_mfma_f32_16x16x32_bf16(a1, b, acc[1][ct], 0, 0, 0);
      }
    }
#pragma unroll
    for (int mt = 0; mt < 2; ++mt) {
#pragma unroll
      for (int ct = 0; ct < 4; ++ct) {
        float bgc = bia[768 + col0 + ct * 16];
#pragma unroll
        for (int i = 0; i < 4; ++i)
          gv[mt][ct][i] = sigmoidf_(acc[mt][ct][i] + bgc);
      }
    }
  }

  // ---------------- P5: lin pass (K=256) + epilogue ----------------
  {
    f32x4 acc[2][4] = {};
#pragma unroll
    for (int ks = 0; ks < 8; ++ks) {
      bf16x8 a0 = ldsA(0, ks), a1 = ldsA(1, ks);
#pragma unroll
      for (int ct = 0; ct < 4; ++ct) {
        bf16x8 b = ldB(Lw, 8, ct, ks);
        acc[0][ct] = __builtin_amdgcn_mfma_f32_16x16x32_bf16(a0, b, acc[0][ct], 0, 0, 0);
        acc[1][ct] = __builtin_amdgcn_mfma_f32_16x16x32_bf16(a1, b, acc[1][ct], 0, 0, 0);
      }
    }
    // out = z*(lv*gv) + part
#pragma unroll
    for (int mt = 0; mt < 2; ++mt) {
#pragma unroll
      for (int ct = 0; ct < 4; ++ct) {
        int cg = col0 + ct * 16;
        float blc = bia[1024 + cg];
#pragma unroll
        for (int ii = 0; ii < 2; ++ii) {
          unsigned int zp = zpk[(mt * 4 + ct) * 2 + ii];
          unsigned int pp = part[(mt * 4 + ct) * 2 + ii];
#pragma unroll
          for (int j = 0; j < 2; ++j) {
            int i = 2 * ii + j;
            int rl = mt * 16 + q * 4 + i;
            float lv = acc[mt][ct][i] + blc;
            float cand = lv * gv[mt][ct][i];
            float zv = bf2f((unsigned short)(j == 0 ? (zp & 0xffffu) : (zp >> 16)));
            float pv = bf2f((unsigned short)(j == 0 ? (pp & 0xffffu) : (pp >> 16)));
            out[(row0 + rl) * 256 + cg] = zv * cand + pv;
          }
        }
      }
    }
  }
}

extern "C" void kernel_launch(void* const* d_in, const int* in_sizes, int n_in,
                              void* d_out, int out_size, void* d_ws, size_t ws_size,
                              hipStream_t stream) {
  const float* x   = (const float*)d_in[0];
  const float* h   = (const float*)d_in[1];
  const float* Wz  = (const float*)d_in[2];  const float* bWz = (const float*)d_in[3];
  const float* Uz  = (const float*)d_in[4];  const float* bUz = (const float*)d_in[5];
  const float* Wr  = (const float*)d_in[6];  const float* bWr = (const float*)d_in[7];
  const float* Ur  = (const float*)d_in[8];  const float* bUr = (const float*)d_in[9];
  const float* Wh  = (const float*)d_in[10]; const float* bWh = (const float*)d_in[11];
  const float* Uh  = (const float*)d_in[12]; const float* bUh = (const float*)d_in[13];
  const float* G   = (const float*)d_in[14]; const float* bG  = (const float*)d_in[15];
  const float* L   = (const float*)d_in[16]; const float* bL  = (const float*)d_in[17];
  const float* bh  = (const float*)d_in[18];

  unsigned short* wb = (unsigned short*)d_ws;
  float* bia = (float*)((char*)d_ws + 1048576);

  wconv_kernel<<<256, 256, 0, stream>>>(Wz, Uz, Wr, Ur, Wh, Uh, G, L,
                                        bWz, bUz, bWr, bUr, bWh, bUh, bG, bL, bh,
                                        wb, bia);

  int rows = in_sizes[0] / 256;        // 200000
  int grid = rows / 32;                // 6250 (exact)
  gru_kernel<<<grid, 256, 0, stream>>>(x, h, wb, bia, (float*)d_out);
}

// Round 8
// 549.186 us; speedup vs baseline: 1.5012x; 1.5012x over previous
//
#include <hip/hip_runtime.h>
#include <hip/hip_bf16.h>

// Fused GRU-like cell: 200000 rows, IN=HID=256, fp32 in/out, bf16 MFMA compute.
// Kernel 1 (wconv): fp32->bf16 weights, fragment-packed; combined biases.
// Kernel 2 (gru): BM=64 rows/block, 512 threads (8 waves), LDS 64 KB ->
//   2 blocks/CU at launch_bounds(512,4).
//   KEY: zero persistent arch-register state. The z accumulator stays in
//   AGPRs through P23 (AGPR peak 64 in every pass), then z is written to the
//   LDS region that rh just vacated. Epilogue: out = z*(cand-h) + h with h
//   re-read from global fp32 (same-XCD L2 hit) preloaded before P45.
//   P1 : az,ar = [x|h]Bz^T,[x|h]Br^T (K=512); tail: rh=sig(ar)*h -> h-region
//   P23: ac = [x|rh]Bh^T (K=512); tail: cand->x-region, z=sig(az)->h-region
//   P45: ag,al = cand G^T, cand L^T (K=256, merged)
//   epi: out = z*(sig(ag+bg)*(al+bl) - h) + h

typedef short bf16x8 __attribute__((ext_vector_type(8)));   // 8 bf16 = 4 VGPRs
typedef float f32x4  __attribute__((ext_vector_type(4)));

__device__ __forceinline__ unsigned int rne_bf16(float f) {
  unsigned int u = __builtin_bit_cast(unsigned int, f);
  return (u + 0x7fffu + ((u >> 16) & 1u)) >> 16;
}
__device__ __forceinline__ unsigned int pack2(float a, float b) {
  return rne_bf16(a) | (rne_bf16(b) << 16);
}
__device__ __forceinline__ float bf2f(unsigned short s) {
  unsigned int u = ((unsigned int)s) << 16;
  return __builtin_bit_cast(float, u);
}
__device__ __forceinline__ float sigmoidf_(float v) {
  return 1.f / (1.f + __expf(-v));
}

// Fragment packing: frag f holds 8 bf16 for lane=f&63 of tile (nt,kt):
// f = base + (nt*KT + kt)*64 + lane, n = nt*16+(lane&15), k = kt*32+(lane>>4)*8.
// Frag bases (in frags): Bz 0, Br 16384, Bh 32768, G 49152, L 57344.
// fp32 biases at byte 1048576.
__global__ void wconv_kernel(const float* Wz, const float* Uz, const float* Wr, const float* Ur,
                             const float* Wh, const float* Uh, const float* G, const float* L,
                             const float* bWz, const float* bUz, const float* bWr, const float* bUr,
                             const float* bWh, const float* bUh, const float* bG, const float* bL,
                             const float* bias_h,
                             unsigned short* wb, float* bout) {
  int f = blockIdx.x * blockDim.x + threadIdx.x;   // 65536 fragments
  const float* A; const float* B = nullptr;
  int rel; bool k512;
  if (f < 16384)      { A = Wz; B = Uz; rel = f;         k512 = true;  }
  else if (f < 32768) { A = Wr; B = Ur; rel = f - 16384; k512 = true;  }
  else if (f < 49152) { A = Wh; B = Uh; rel = f - 32768; k512 = true;  }
  else if (f < 57344) { A = G;          rel = f - 49152; k512 = false; }
  else                { A = L;          rel = f - 57344; k512 = false; }
  int lane = rel & 63, tile = rel >> 6;
  int kt = k512 ? (tile & 15) : (tile & 7);
  int nt = k512 ? (tile >> 4) : (tile >> 3);
  int n = nt * 16 + (lane & 15);
  int k0 = kt * 32 + (lane >> 4) * 8;
  unsigned short tmp[8];
#pragma unroll
  for (int j = 0; j < 8; ++j) {
    int k = k0 + j;
    float v = (k < 256) ? A[n * 256 + k] : B[n * 256 + (k - 256)];
    tmp[j] = (unsigned short)rne_bf16(v);
  }
  *reinterpret_cast<uint4*>(wb + (size_t)f * 8) = *reinterpret_cast<const uint4*>(tmp);

  if (f < 256) {
    bout[f]        = bWz[f] + bUz[f];
    bout[256 + f]  = bWr[f] + bUr[f];
    bout[512 + f]  = bWh[f] + bUh[f] + bias_h[f];
    bout[768 + f]  = bG[f];
    bout[1024 + f] = bL[f];
  }
}

// Main fused kernel. 512 threads (8 waves). BM=64 rows/block.
// Wave w owns output cols [32w, 32w+32) (ct=0..1). MFMA 16x16x32 bf16.
// LDS xh[64][512] bf16, XOR-swizzled 16B chunks: chunks 0..31 = x -> cand,
// chunks 32..63 = h -> rh -> z.
__global__ __launch_bounds__(512, 4) void gru_kernel(
    const float* __restrict__ x, const float* __restrict__ h,
    const unsigned short* __restrict__ wb,
    const float* __restrict__ bia,
    float* __restrict__ out)
{
  __shared__ unsigned short xh[64 * 512];    // 64 KB

  const int tid  = threadIdx.x;
  const int lane = tid & 63;
  const int wave = tid >> 6;
  const int q    = lane >> 4;     // quarter-wave id
  const int lr   = lane & 15;
  const long row0 = (long)blockIdx.x * 64;

  // ---------------- P0: stage x,h -> LDS bf16 (swizzled) ----------------
#pragma unroll
  for (int i = 0; i < 4; ++i) {
    int c = tid + i * 512;               // 64 rows x 32 chunks
    int r = c >> 5, c8 = c & 31;
    const float4* p = reinterpret_cast<const float4*>(x + (row0 + r) * 256 + c8 * 8);
    float4 v0 = p[0], v1 = p[1];
    uint4 w;
    w.x = pack2(v0.x, v0.y); w.y = pack2(v0.z, v0.w);
    w.z = pack2(v1.x, v1.y); w.w = pack2(v1.z, v1.w);
    reinterpret_cast<uint4*>(xh)[r * 64 + (c8 ^ (r & 7))] = w;
  }
#pragma unroll
  for (int i = 0; i < 4; ++i) {
    int c = tid + i * 512;
    int r = c >> 5, c8 = c & 31;
    const float4* p = reinterpret_cast<const float4*>(h + (row0 + r) * 256 + c8 * 8);
    float4 v0 = p[0], v1 = p[1];
    uint4 w;
    w.x = pack2(v0.x, v0.y); w.y = pack2(v0.z, v0.w);
    w.z = pack2(v1.x, v1.y); w.w = pack2(v1.z, v1.w);
    reinterpret_cast<uint4*>(xh)[r * 64 + ((32 + c8) ^ (r & 7))] = w;
  }
  __syncthreads();

  const unsigned short* Bz = wb;                    // frag-packed bases (shorts)
  const unsigned short* Br = wb + 131072;
  const unsigned short* Bh = wb + 262144;
  const unsigned short* Gw = wb + 393216;
  const unsigned short* Lw = wb + 458752;

  auto ldsA = [&](int mt, int ks) -> bf16x8 {  // A frag, chunk ks*4+q
    int r = mt * 16 + lr;
    int kc = ks * 4 + q;
    return reinterpret_cast<const bf16x8*>(xh)[r * 64 + (kc ^ (r & 7))];
  };
  auto ldB = [&](const unsigned short* base, int KT, int ct, int ks) -> bf16x8 {
    int nt = wave * 2 + ct;
    return reinterpret_cast<const bf16x8*>(base)[(nt * KT + ks) * 64 + lane];
  };

  const int col0 = wave * 32 + lr;      // ct=0 column

  // ---------------- P1: merged z + r (K=512), az parked in AGPRs ----------------
  f32x4 az[4][2] = {};
  {
    f32x4 ar[4][2] = {};
#pragma unroll 1
    for (int ks = 0; ks < 16; ++ks) {
      bf16x8 a0 = ldsA(0, ks), a1 = ldsA(1, ks), a2 = ldsA(2, ks), a3 = ldsA(3, ks);
      {
        bf16x8 b0 = ldB(Bz, 16, 0, ks), b1 = ldB(Bz, 16, 1, ks);
        az[0][0] = __builtin_amdgcn_mfma_f32_16x16x32_bf16(a0, b0, az[0][0], 0, 0, 0);
        az[1][0] = __builtin_amdgcn_mfma_f32_16x16x32_bf16(a1, b0, az[1][0], 0, 0, 0);
        az[2][0] = __builtin_amdgcn_mfma_f32_16x16x32_bf16(a2, b0, az[2][0], 0, 0, 0);
        az[3][0] = __builtin_amdgcn_mfma_f32_16x16x32_bf16(a3, b0, az[3][0], 0, 0, 0);
        az[0][1] = __builtin_amdgcn_mfma_f32_16x16x32_bf16(a0, b1, az[0][1], 0, 0, 0);
        az[1][1] = __builtin_amdgcn_mfma_f32_16x16x32_bf16(a1, b1, az[1][1], 0, 0, 0);
        az[2][1] = __builtin_amdgcn_mfma_f32_16x16x32_bf16(a2, b1, az[2][1], 0, 0, 0);
        az[3][1] = __builtin_amdgcn_mfma_f32_16x16x32_bf16(a3, b1, az[3][1], 0, 0, 0);
      }
      {
        bf16x8 b0 = ldB(Br, 16, 0, ks), b1 = ldB(Br, 16, 1, ks);
        ar[0][0] = __builtin_amdgcn_mfma_f32_16x16x32_bf16(a0, b0, ar[0][0], 0, 0, 0);
        ar[1][0] = __builtin_amdgcn_mfma_f32_16x16x32_bf16(a1, b0, ar[1][0], 0, 0, 0);
        ar[2][0] = __builtin_amdgcn_mfma_f32_16x16x32_bf16(a2, b0, ar[2][0], 0, 0, 0);
        ar[3][0] = __builtin_amdgcn_mfma_f32_16x16x32_bf16(a3, b0, ar[3][0], 0, 0, 0);
        ar[0][1] = __builtin_amdgcn_mfma_f32_16x16x32_bf16(a0, b1, ar[0][1], 0, 0, 0);
        ar[1][1] = __builtin_amdgcn_mfma_f32_16x16x32_bf16(a1, b1, ar[1][1], 0, 0, 0);
        ar[2][1] = __builtin_amdgcn_mfma_f32_16x16x32_bf16(a2, b1, ar[2][1], 0, 0, 0);
        ar[3][1] = __builtin_amdgcn_mfma_f32_16x16x32_bf16(a3, b1, ar[3][1], 0, 0, 0);
      }
    }
    __syncthreads();   // all waves done reading h-region A-frags
    // tail: rh = sigmoid(ar + brc) * h  -> h-region, same-thread RMW (safe)
#pragma unroll
    for (int mt = 0; mt < 4; ++mt) {
#pragma unroll
      for (int ct = 0; ct < 2; ++ct) {
        int cg = col0 + ct * 16;
        float brc = bia[256 + cg];
        int hc = 32 + (cg >> 3);
#pragma unroll
        for (int i = 0; i < 4; ++i) {
          int rl = mt * 16 + q * 4 + i;
          int adr = rl * 512 + (hc ^ (rl & 7)) * 8 + (cg & 7);
          float hv = bf2f(xh[adr]);
          float rv = sigmoidf_(ar[mt][ct][i] + brc);
          xh[adr] = (unsigned short)rne_bf16(rv * hv);
        }
      }
    }
  }
  __syncthreads();

  // ---------------- P23: ac = [x|rh] @ Bh^T (K=512); az still parked ----------------
  {
    f32x4 ac[4][2] = {};
#pragma unroll 1
    for (int ks = 0; ks < 16; ++ks) {
      bf16x8 a0 = ldsA(0, ks), a1 = ldsA(1, ks), a2 = ldsA(2, ks), a3 = ldsA(3, ks);
      bf16x8 b0 = ldB(Bh, 16, 0, ks), b1 = ldB(Bh, 16, 1, ks);
      ac[0][0] = __builtin_amdgcn_mfma_f32_16x16x32_bf16(a0, b0, ac[0][0], 0, 0, 0);
      ac[1][0] = __builtin_amdgcn_mfma_f32_16x16x32_bf16(a1, b0, ac[1][0], 0, 0, 0);
      ac[2][0] = __builtin_amdgcn_mfma_f32_16x16x32_bf16(a2, b0, ac[2][0], 0, 0, 0);
      ac[3][0] = __builtin_amdgcn_mfma_f32_16x16x32_bf16(a3, b0, ac[3][0], 0, 0, 0);
      ac[0][1] = __builtin_amdgcn_mfma_f32_16x16x32_bf16(a0, b1, ac[0][1], 0, 0, 0);
      ac[1][1] = __builtin_amdgcn_mfma_f32_16x16x32_bf16(a1, b1, ac[1][1], 0, 0, 0);
      ac[2][1] = __builtin_amdgcn_mfma_f32_16x16x32_bf16(a2, b1, ac[2][1], 0, 0, 0);
      ac[3][1] = __builtin_amdgcn_mfma_f32_16x16x32_bf16(a3, b1, ac[3][1], 0, 0, 0);
    }
    __syncthreads();   // all waves done reading x-region + rh A-frags
    // tail: cand -> x-region; z = sigmoid(az + bz) -> h-region (rh now dead)
#pragma unroll
    for (int mt = 0; mt < 4; ++mt) {
#pragma unroll
      for (int ct = 0; ct < 2; ++ct) {
        int cg = col0 + ct * 16;
        float bcc = bia[512 + cg];
        float bzc = bia[cg];
        int hc = 32 + (cg >> 3);
#pragma unroll
        for (int i = 0; i < 4; ++i) {
          int rl = mt * 16 + q * 4 + i;
          float cd = ac[mt][ct][i] + bcc;
          xh[rl * 512 + (((cg >> 3) ^ (rl & 7)) * 8) + (cg & 7)] = (unsigned short)rne_bf16(cd);
          float zv = sigmoidf_(az[mt][ct][i] + bzc);
          xh[rl * 512 + (hc ^ (rl & 7)) * 8 + (cg & 7)] = (unsigned short)rne_bf16(zv);
        }
      }
    }
  }
  __syncthreads();

  // preload h (global fp32, same-XCD L2) for the epilogue
  float hreg[4][2][4];
#pragma unroll
  for (int mt = 0; mt < 4; ++mt)
#pragma unroll
    for (int ct = 0; ct < 2; ++ct)
#pragma unroll
      for (int i = 0; i < 4; ++i) {
        int rl = mt * 16 + q * 4 + i;
        hreg[mt][ct][i] = h[(row0 + rl) * 256 + col0 + ct * 16];
      }

  // ---------------- P45: merged gate + linear (K=256, cand region) ----------------
  {
    f32x4 ag[4][2] = {}; f32x4 al[4][2] = {};
#pragma unroll 1
    for (int ks = 0; ks < 8; ++ks) {
      bf16x8 a0 = ldsA(0, ks), a1 = ldsA(1, ks), a2 = ldsA(2, ks), a3 = ldsA(3, ks);
      {
        bf16x8 b0 = ldB(Gw, 8, 0, ks), b1 = ldB(Gw, 8, 1, ks);
        ag[0][0] = __builtin_amdgcn_mfma_f32_16x16x32_bf16(a0, b0, ag[0][0], 0, 0, 0);
        ag[1][0] = __builtin_amdgcn_mfma_f32_16x16x32_bf16(a1, b0, ag[1][0], 0, 0, 0);
        ag[2][0] = __builtin_amdgcn_mfma_f32_16x16x32_bf16(a2, b0, ag[2][0], 0, 0, 0);
        ag[3][0] = __builtin_amdgcn_mfma_f32_16x16x32_bf16(a3, b0, ag[3][0], 0, 0, 0);
        ag[0][1] = __builtin_amdgcn_mfma_f32_16x16x32_bf16(a0, b1, ag[0][1], 0, 0, 0);
        ag[1][1] = __builtin_amdgcn_mfma_f32_16x16x32_bf16(a1, b1, ag[1][1], 0, 0, 0);
        ag[2][1] = __builtin_amdgcn_mfma_f32_16x16x32_bf16(a2, b1, ag[2][1], 0, 0, 0);
        ag[3][1] = __builtin_amdgcn_mfma_f32_16x16x32_bf16(a3, b1, ag[3][1], 0, 0, 0);
      }
      {
        bf16x8 b0 = ldB(Lw, 8, 0, ks), b1 = ldB(Lw, 8, 1, ks);
        al[0][0] = __builtin_amdgcn_mfma_f32_16x16x32_bf16(a0, b0, al[0][0], 0, 0, 0);
        al[1][0] = __builtin_amdgcn_mfma_f32_16x16x32_bf16(a1, b0, al[1][0], 0, 0, 0);
        al[2][0] = __builtin_amdgcn_mfma_f32_16x16x32_bf16(a2, b0, al[2][0], 0, 0, 0);
        al[3][0] = __builtin_amdgcn_mfma_f32_16x16x32_bf16(a3, b0, al[3][0], 0, 0, 0);
        al[0][1] = __builtin_amdgcn_mfma_f32_16x16x32_bf16(a0, b1, al[0][1], 0, 0, 0);
        al[1][1] = __builtin_amdgcn_mfma_f32_16x16x32_bf16(a1, b1, al[1][1], 0, 0, 0);
        al[2][1] = __builtin_amdgcn_mfma_f32_16x16x32_bf16(a2, b1, al[2][1], 0, 0, 0);
        al[3][1] = __builtin_amdgcn_mfma_f32_16x16x32_bf16(a3, b1, al[3][1], 0, 0, 0);
      }
    }

    // ---------------- epilogue: out = z*(gate*lin - h) + h ----------------
#pragma unroll
    for (int mt = 0; mt < 4; ++mt) {
#pragma unroll
      for (int ct = 0; ct < 2; ++ct) {
        int cg = col0 + ct * 16;
        float bgc = bia[768 + cg];
        float blc = bia[1024 + cg];
        int hc = 32 + (cg >> 3);
#pragma unroll
        for (int i = 0; i < 4; ++i) {
          int rl = mt * 16 + q * 4 + i;
          float gvv = sigmoidf_(ag[mt][ct][i] + bgc);
          float lv  = al[mt][ct][i] + blc;
          float cnd = lv * gvv;
          float zv  = bf2f(xh[rl * 512 + (hc ^ (rl & 7)) * 8 + (cg & 7)]);
          float hv  = hreg[mt][ct][i];
          out[(row0 + rl) * 256 + cg] = zv * (cnd - hv) + hv;
        }
      }
    }
  }
}

extern "C" void kernel_launch(void* const* d_in, const int* in_sizes, int n_in,
                              void* d_out, int out_size, void* d_ws, size_t ws_size,
                              hipStream_t stream) {
  const float* x   = (const float*)d_in[0];
  const float* h   = (const float*)d_in[1];
  const float* Wz  = (const float*)d_in[2];  const float* bWz = (const float*)d_in[3];
  const float* Uz  = (const float*)d_in[4];  const float* bUz = (const float*)d_in[5];
  const float* Wr  = (const float*)d_in[6];  const float* bWr = (const float*)d_in[7];
  const float* Ur  = (const float*)d_in[8];  const float* bUr = (const float*)d_in[9];
  const float* Wh  = (const float*)d_in[10]; const float* bWh = (const float*)d_in[11];
  const float* Uh  = (const float*)d_in[12]; const float* bUh = (const float*)d_in[13];
  const float* G   = (const float*)d_in[14]; const float* bG  = (const float*)d_in[15];
  const float* L   = (const float*)d_in[16]; const float* bL  = (const float*)d_in[17];
  const float* bh  = (const float*)d_in[18];

  unsigned short* wb = (unsigned short*)d_ws;
  float* bia = (float*)((char*)d_ws + 1048576);

  wconv_kernel<<<256, 256, 0, stream>>>(Wz, Uz, Wr, Ur, Wh, Uh, G, L,
                                        bWz, bUz, bWr, bUr, bWh, bUh, bG, bL, bh,
                                        wb, bia);

  int rows = in_sizes[0] / 256;        // 200000
  int grid = rows / 64;                // 3125 (exact)
  gru_kernel<<<grid, 512, 0, stream>>>(x, h, wb, bia, (float*)d_out);
}

// Round 9
// 510.421 us; speedup vs baseline: 1.6152x; 1.0759x over previous
//
#include <hip/hip_runtime.h>
#include <hip/hip_bf16.h>

// Fused GRU-like cell: 200000 rows, IN=HID=256, fp32 in/out, bf16 MFMA compute.
// Kernel 1 (wconv): fp32->bf16 weights, fragment-packed; combined biases.
// Kernel 2 (gru): BM=64 rows/block, 512 threads (8 waves), LDS 64 KB ->
//   2 blocks/CU at launch_bounds(512,4); budget split is 64 arch + 64 AGPR.
//   Discipline: AGPR peak exactly 64 in every pass; arch-side peak <= ~50
//   (no persistent packed state, no preloaded h, capped in-flight load sets).
//   P1 : az,ar = [x|h]Bz^T,[x|h]Br^T (K=512); tail: rh=sig(ar)*h -> h-region
//   P23: ac = [x|rh]Bh^T (K=512); tail: cand->x-region, z=sig(az)->h-region
//   P45: ag,al = cand G^T, cand L^T (K=256, merged)
//   epi: out = z*(sig(ag+bg)*(al+bl) - h) + h   (h read inline from global)

typedef short bf16x8 __attribute__((ext_vector_type(8)));   // 8 bf16 = 4 VGPRs
typedef float f32x4  __attribute__((ext_vector_type(4)));

__device__ __forceinline__ unsigned int rne_bf16(float f) {
  unsigned int u = __builtin_bit_cast(unsigned int, f);
  return (u + 0x7fffu + ((u >> 16) & 1u)) >> 16;
}
__device__ __forceinline__ unsigned int pack2(float a, float b) {
  return rne_bf16(a) | (rne_bf16(b) << 16);
}
__device__ __forceinline__ float bf2f(unsigned short s) {
  unsigned int u = ((unsigned int)s) << 16;
  return __builtin_bit_cast(float, u);
}
__device__ __forceinline__ float sigmoidf_(float v) {
  return 1.f / (1.f + __expf(-v));
}

// Fragment packing: frag f holds 8 bf16 for lane=f&63 of tile (nt,kt):
// f = base + (nt*KT + kt)*64 + lane, n = nt*16+(lane&15), k = kt*32+(lane>>4)*8.
// Frag bases (in frags): Bz 0, Br 16384, Bh 32768, G 49152, L 57344.
// fp32 biases at byte 1048576.
__global__ void wconv_kernel(const float* Wz, const float* Uz, const float* Wr, const float* Ur,
                             const float* Wh, const float* Uh, const float* G, const float* L,
                             const float* bWz, const float* bUz, const float* bWr, const float* bUr,
                             const float* bWh, const float* bUh, const float* bG, const float* bL,
                             const float* bias_h,
                             unsigned short* wb, float* bout) {
  int f = blockIdx.x * blockDim.x + threadIdx.x;   // 65536 fragments
  const float* A; const float* B = nullptr;
  int rel; bool k512;
  if (f < 16384)      { A = Wz; B = Uz; rel = f;         k512 = true;  }
  else if (f < 32768) { A = Wr; B = Ur; rel = f - 16384; k512 = true;  }
  else if (f < 49152) { A = Wh; B = Uh; rel = f - 32768; k512 = true;  }
  else if (f < 57344) { A = G;          rel = f - 49152; k512 = false; }
  else                { A = L;          rel = f - 57344; k512 = false; }
  int lane = rel & 63, tile = rel >> 6;
  int kt = k512 ? (tile & 15) : (tile & 7);
  int nt = k512 ? (tile >> 4) : (tile >> 3);
  int n = nt * 16 + (lane & 15);
  int k0 = kt * 32 + (lane >> 4) * 8;
  unsigned short tmp[8];
#pragma unroll
  for (int j = 0; j < 8; ++j) {
    int k = k0 + j;
    float v = (k < 256) ? A[n * 256 + k] : B[n * 256 + (k - 256)];
    tmp[j] = (unsigned short)rne_bf16(v);
  }
  *reinterpret_cast<uint4*>(wb + (size_t)f * 8) = *reinterpret_cast<const uint4*>(tmp);

  if (f < 256) {
    bout[f]        = bWz[f] + bUz[f];
    bout[256 + f]  = bWr[f] + bUr[f];
    bout[512 + f]  = bWh[f] + bUh[f] + bias_h[f];
    bout[768 + f]  = bG[f];
    bout[1024 + f] = bL[f];
  }
}

// Main fused kernel. 512 threads (8 waves). BM=64 rows/block.
// Wave w owns output cols [32w, 32w+32) (ct=0..1). MFMA 16x16x32 bf16.
// LDS xh[64][512] bf16, XOR-swizzled 16B chunks: chunks 0..31 = x -> cand,
// chunks 32..63 = h -> rh -> z.
__global__ __launch_bounds__(512, 4) void gru_kernel(
    const float* __restrict__ x, const float* __restrict__ h,
    const unsigned short* __restrict__ wb,
    const float* __restrict__ bia,
    float* __restrict__ out)
{
  __shared__ unsigned short xh[64 * 512];    // 64 KB

  const int tid  = threadIdx.x;
  const int lane = tid & 63;
  const int wave = tid >> 6;
  const int q    = lane >> 4;     // quarter-wave id
  const int lr   = lane & 15;
  const long row0 = (long)blockIdx.x * 64;

  // ---------------- P0: stage x,h -> LDS bf16 (swizzled) ----------------
#pragma unroll 2
  for (int i = 0; i < 4; ++i) {
    int c = tid + i * 512;               // 64 rows x 32 chunks
    int r = c >> 5, c8 = c & 31;
    const float4* p = reinterpret_cast<const float4*>(x + (row0 + r) * 256 + c8 * 8);
    float4 v0 = p[0], v1 = p[1];
    uint4 w;
    w.x = pack2(v0.x, v0.y); w.y = pack2(v0.z, v0.w);
    w.z = pack2(v1.x, v1.y); w.w = pack2(v1.z, v1.w);
    reinterpret_cast<uint4*>(xh)[r * 64 + (c8 ^ (r & 7))] = w;
  }
#pragma unroll 2
  for (int i = 0; i < 4; ++i) {
    int c = tid + i * 512;
    int r = c >> 5, c8 = c & 31;
    const float4* p = reinterpret_cast<const float4*>(h + (row0 + r) * 256 + c8 * 8);
    float4 v0 = p[0], v1 = p[1];
    uint4 w;
    w.x = pack2(v0.x, v0.y); w.y = pack2(v0.z, v0.w);
    w.z = pack2(v1.x, v1.y); w.w = pack2(v1.z, v1.w);
    reinterpret_cast<uint4*>(xh)[r * 64 + ((32 + c8) ^ (r & 7))] = w;
  }
  __syncthreads();

  const unsigned short* Bz = wb;                    // frag-packed bases (shorts)
  const unsigned short* Br = wb + 131072;
  const unsigned short* Bh = wb + 262144;
  const unsigned short* Gw = wb + 393216;
  const unsigned short* Lw = wb + 458752;

  auto ldsA = [&](int mt, int ks) -> bf16x8 {  // A frag, chunk ks*4+q
    int r = mt * 16 + lr;
    int kc = ks * 4 + q;
    return reinterpret_cast<const bf16x8*>(xh)[r * 64 + (kc ^ (r & 7))];
  };
  auto ldB = [&](const unsigned short* base, int KT, int ct, int ks) -> bf16x8 {
    int nt = wave * 2 + ct;
    return reinterpret_cast<const bf16x8*>(base)[(nt * KT + ks) * 64 + lane];
  };

  const int col0 = wave * 32 + lr;      // ct=0 column

  // ---------------- P1: merged z + r (K=512), az parked in AGPRs ----------------
  f32x4 az[4][2] = {};
  {
    f32x4 ar[4][2] = {};
#pragma unroll 1
    for (int ks = 0; ks < 16; ++ks) {
      bf16x8 a0 = ldsA(0, ks), a1 = ldsA(1, ks), a2 = ldsA(2, ks), a3 = ldsA(3, ks);
      {
        bf16x8 b0 = ldB(Bz, 16, 0, ks), b1 = ldB(Bz, 16, 1, ks);
        az[0][0] = __builtin_amdgcn_mfma_f32_16x16x32_bf16(a0, b0, az[0][0], 0, 0, 0);
        az[1][0] = __builtin_amdgcn_mfma_f32_16x16x32_bf16(a1, b0, az[1][0], 0, 0, 0);
        az[2][0] = __builtin_amdgcn_mfma_f32_16x16x32_bf16(a2, b0, az[2][0], 0, 0, 0);
        az[3][0] = __builtin_amdgcn_mfma_f32_16x16x32_bf16(a3, b0, az[3][0], 0, 0, 0);
        az[0][1] = __builtin_amdgcn_mfma_f32_16x16x32_bf16(a0, b1, az[0][1], 0, 0, 0);
        az[1][1] = __builtin_amdgcn_mfma_f32_16x16x32_bf16(a1, b1, az[1][1], 0, 0, 0);
        az[2][1] = __builtin_amdgcn_mfma_f32_16x16x32_bf16(a2, b1, az[2][1], 0, 0, 0);
        az[3][1] = __builtin_amdgcn_mfma_f32_16x16x32_bf16(a3, b1, az[3][1], 0, 0, 0);
      }
      {
        bf16x8 b0 = ldB(Br, 16, 0, ks), b1 = ldB(Br, 16, 1, ks);
        ar[0][0] = __builtin_amdgcn_mfma_f32_16x16x32_bf16(a0, b0, ar[0][0], 0, 0, 0);
        ar[1][0] = __builtin_amdgcn_mfma_f32_16x16x32_bf16(a1, b0, ar[1][0], 0, 0, 0);
        ar[2][0] = __builtin_amdgcn_mfma_f32_16x16x32_bf16(a2, b0, ar[2][0], 0, 0, 0);
        ar[3][0] = __builtin_amdgcn_mfma_f32_16x16x32_bf16(a3, b0, ar[3][0], 0, 0, 0);
        ar[0][1] = __builtin_amdgcn_mfma_f32_16x16x32_bf16(a0, b1, ar[0][1], 0, 0, 0);
        ar[1][1] = __builtin_amdgcn_mfma_f32_16x16x32_bf16(a1, b1, ar[1][1], 0, 0, 0);
        ar[2][1] = __builtin_amdgcn_mfma_f32_16x16x32_bf16(a2, b1, ar[2][1], 0, 0, 0);
        ar[3][1] = __builtin_amdgcn_mfma_f32_16x16x32_bf16(a3, b1, ar[3][1], 0, 0, 0);
      }
    }
    __syncthreads();   // all waves done reading h-region A-frags
    // tail: rh = sigmoid(ar + brc) * h  -> h-region, same-thread RMW (safe)
#pragma unroll 1
    for (int mt = 0; mt < 4; ++mt) {
#pragma unroll
      for (int ct = 0; ct < 2; ++ct) {
        int cg = col0 + ct * 16;
        float brc = bia[256 + cg];
        int hc = 32 + (cg >> 3);
#pragma unroll
        for (int i = 0; i < 4; ++i) {
          int rl = mt * 16 + q * 4 + i;
          int adr = rl * 512 + (hc ^ (rl & 7)) * 8 + (cg & 7);
          float hv = bf2f(xh[adr]);
          float rv = sigmoidf_(ar[mt][ct][i] + brc);
          xh[adr] = (unsigned short)rne_bf16(rv * hv);
        }
      }
    }
  }
  __syncthreads();

  // ---------------- P23: ac = [x|rh] @ Bh^T (K=512); az still parked ----------------
  {
    f32x4 ac[4][2] = {};
#pragma unroll 1
    for (int ks = 0; ks < 16; ++ks) {
      bf16x8 a0 = ldsA(0, ks), a1 = ldsA(1, ks), a2 = ldsA(2, ks), a3 = ldsA(3, ks);
      bf16x8 b0 = ldB(Bh, 16, 0, ks), b1 = ldB(Bh, 16, 1, ks);
      ac[0][0] = __builtin_amdgcn_mfma_f32_16x16x32_bf16(a0, b0, ac[0][0], 0, 0, 0);
      ac[1][0] = __builtin_amdgcn_mfma_f32_16x16x32_bf16(a1, b0, ac[1][0], 0, 0, 0);
      ac[2][0] = __builtin_amdgcn_mfma_f32_16x16x32_bf16(a2, b0, ac[2][0], 0, 0, 0);
      ac[3][0] = __builtin_amdgcn_mfma_f32_16x16x32_bf16(a3, b0, ac[3][0], 0, 0, 0);
      ac[0][1] = __builtin_amdgcn_mfma_f32_16x16x32_bf16(a0, b1, ac[0][1], 0, 0, 0);
      ac[1][1] = __builtin_amdgcn_mfma_f32_16x16x32_bf16(a1, b1, ac[1][1], 0, 0, 0);
      ac[2][1] = __builtin_amdgcn_mfma_f32_16x16x32_bf16(a2, b1, ac[2][1], 0, 0, 0);
      ac[3][1] = __builtin_amdgcn_mfma_f32_16x16x32_bf16(a3, b1, ac[3][1], 0, 0, 0);
    }
    __syncthreads();   // all waves done reading x-region + rh A-frags
    // tail: cand -> x-region; z = sigmoid(az + bz) -> h-region (rh now dead)
#pragma unroll 1
    for (int mt = 0; mt < 4; ++mt) {
#pragma unroll
      for (int ct = 0; ct < 2; ++ct) {
        int cg = col0 + ct * 16;
        float bcc = bia[512 + cg];
        float bzc = bia[cg];
        int hc = 32 + (cg >> 3);
#pragma unroll
        for (int i = 0; i < 4; ++i) {
          int rl = mt * 16 + q * 4 + i;
          float cd = ac[mt][ct][i] + bcc;
          xh[rl * 512 + (((cg >> 3) ^ (rl & 7)) * 8) + (cg & 7)] = (unsigned short)rne_bf16(cd);
          float zv = sigmoidf_(az[mt][ct][i] + bzc);
          xh[rl * 512 + (hc ^ (rl & 7)) * 8 + (cg & 7)] = (unsigned short)rne_bf16(zv);
        }
      }
    }
  }
  __syncthreads();

  // ---------------- P45: merged gate + linear (K=256, cand region) ----------------
  {
    f32x4 ag[4][2] = {}; f32x4 al[4][2] = {};
#pragma unroll 1
    for (int ks = 0; ks < 8; ++ks) {
      bf16x8 a0 = ldsA(0, ks), a1 = ldsA(1, ks), a2 = ldsA(2, ks), a3 = ldsA(3, ks);
      {
        bf16x8 b0 = ldB(Gw, 8, 0, ks), b1 = ldB(Gw, 8, 1, ks);
        ag[0][0] = __builtin_amdgcn_mfma_f32_16x16x32_bf16(a0, b0, ag[0][0], 0, 0, 0);
        ag[1][0] = __builtin_amdgcn_mfma_f32_16x16x32_bf16(a1, b0, ag[1][0], 0, 0, 0);
        ag[2][0] = __builtin_amdgcn_mfma_f32_16x16x32_bf16(a2, b0, ag[2][0], 0, 0, 0);
        ag[3][0] = __builtin_amdgcn_mfma_f32_16x16x32_bf16(a3, b0, ag[3][0], 0, 0, 0);
        ag[0][1] = __builtin_amdgcn_mfma_f32_16x16x32_bf16(a0, b1, ag[0][1], 0, 0, 0);
        ag[1][1] = __builtin_amdgcn_mfma_f32_16x16x32_bf16(a1, b1, ag[1][1], 0, 0, 0);
        ag[2][1] = __builtin_amdgcn_mfma_f32_16x16x32_bf16(a2, b1, ag[2][1], 0, 0, 0);
        ag[3][1] = __builtin_amdgcn_mfma_f32_16x16x32_bf16(a3, b1, ag[3][1], 0, 0, 0);
      }
      {
        bf16x8 b0 = ldB(Lw, 8, 0, ks), b1 = ldB(Lw, 8, 1, ks);
        al[0][0] = __builtin_amdgcn_mfma_f32_16x16x32_bf16(a0, b0, al[0][0], 0, 0, 0);
        al[1][0] = __builtin_amdgcn_mfma_f32_16x16x32_bf16(a1, b0, al[1][0], 0, 0, 0);
        al[2][0] = __builtin_amdgcn_mfma_f32_16x16x32_bf16(a2, b0, al[2][0], 0, 0, 0);
        al[3][0] = __builtin_amdgcn_mfma_f32_16x16x32_bf16(a3, b0, al[3][0], 0, 0, 0);
        al[0][1] = __builtin_amdgcn_mfma_f32_16x16x32_bf16(a0, b1, al[0][1], 0, 0, 0);
        al[1][1] = __builtin_amdgcn_mfma_f32_16x16x32_bf16(a1, b1, al[1][1], 0, 0, 0);
        al[2][1] = __builtin_amdgcn_mfma_f32_16x16x32_bf16(a2, b1, al[2][1], 0, 0, 0);
        al[3][1] = __builtin_amdgcn_mfma_f32_16x16x32_bf16(a3, b1, al[3][1], 0, 0, 0);
      }
    }

    // ---------------- epilogue: out = z*(gate*lin - h) + h ----------------
    // h read inline from global fp32 (L2-hot: staged by this block in P0)
#pragma unroll 1
    for (int mt = 0; mt < 4; ++mt) {
#pragma unroll
      for (int ct = 0; ct < 2; ++ct) {
        int cg = col0 + ct * 16;
        float bgc = bia[768 + cg];
        float blc = bia[1024 + cg];
        int hc = 32 + (cg >> 3);
#pragma unroll
        for (int i = 0; i < 4; ++i) {
          int rl = mt * 16 + q * 4 + i;
          float gvv = sigmoidf_(ag[mt][ct][i] + bgc);
          float lv  = al[mt][ct][i] + blc;
          float cnd = lv * gvv;
          float zv  = bf2f(xh[rl * 512 + (hc ^ (rl & 7)) * 8 + (cg & 7)]);
          float hv  = h[(row0 + rl) * 256 + cg];
          out[(row0 + rl) * 256 + cg] = zv * (cnd - hv) + hv;
        }
      }
    }
  }
}

extern "C" void kernel_launch(void* const* d_in, const int* in_sizes, int n_in,
                              void* d_out, int out_size, void* d_ws, size_t ws_size,
                              hipStream_t stream) {
  const float* x   = (const float*)d_in[0];
  const float* h   = (const float*)d_in[1];
  const float* Wz  = (const float*)d_in[2];  const float* bWz = (const float*)d_in[3];
  const float* Uz  = (const float*)d_in[4];  const float* bUz = (const float*)d_in[5];
  const float* Wr  = (const float*)d_in[6];  const float* bWr = (const float*)d_in[7];
  const float* Ur  = (const float*)d_in[8];  const float* bUr = (const float*)d_in[9];
  const float* Wh  = (const float*)d_in[10]; const float* bWh = (const float*)d_in[11];
  const float* Uh  = (const float*)d_in[12]; const float* bUh = (const float*)d_in[13];
  const float* G   = (const float*)d_in[14]; const float* bG  = (const float*)d_in[15];
  const float* L   = (const float*)d_in[16]; const float* bL  = (const float*)d_in[17];
  const float* bh  = (const float*)d_in[18];

  unsigned short* wb = (unsigned short*)d_ws;
  float* bia = (float*)((char*)d_ws + 1048576);

  wconv_kernel<<<256, 256, 0, stream>>>(Wz, Uz, Wr, Ur, Wh, Uh, G, L,
                                        bWz, bUz, bWr, bUr, bWh, bUh, bG, bL, bh,
                                        wb, bia);

  int rows = in_sizes[0] / 256;        // 200000
  int grid = rows / 64;                // 3125 (exact)
  gru_kernel<<<grid, 512, 0, stream>>>(x, h, wb, bia, (float*)d_out);
}